// Round 5
// baseline (194.808 us; speedup 1.0000x reference)
//
#include <hip/hip_runtime.h>

// Problem constants: B=32, C=768, H=W=24 -> HW=576
#define B_  32
#define C_  768
#define HW_ 576

#define QK_STEPS 18          // HW_/32 k-chunks
#define PV_STEPS 24          // C_/32 k-chunks
#define A_TILE_B 8192        // 128 rows * 64 B per 32-k chunk
#define V_TILE_B 12288       // 192 rows * 64 B per 32-k chunk

typedef _Float16 half8 __attribute__((ext_vector_type(8)));
typedef _Float16 half4 __attribute__((ext_vector_type(4)));
typedef float    f32x4 __attribute__((ext_vector_type(4)));

// async global->LDS, 16B per lane; lds base wave-uniform, global src per-lane
__device__ __forceinline__ void g2l16(const void* g, void* l) {
    __builtin_amdgcn_global_load_lds(
        (const __attribute__((address_space(1))) unsigned int*)g,
        (__attribute__((address_space(3))) unsigned int*)l, 16, 0, 0);
}

// bijective XCD-aware block swizzle (m204)
__device__ __forceinline__ int xcd_swz(int orig, int nwg) {
    int q = nwg >> 3, rr = nwg & 7;
    int xcd = orig & 7, idx = orig >> 3;
    int base = (xcd < rr) ? xcd * (q + 1) : rr * (q + 1) + (xcd - rr) * q;
    return base + idx;
}

#define LGKM0_BARRIER() do {                                   \
        asm volatile("s_waitcnt lgkmcnt(0)" ::: "memory");     \
        __builtin_amdgcn_s_barrier();                          \
    } while (0)
#define VMCNT_BARRIER(N) do {                                  \
        asm volatile("s_waitcnt vmcnt(" #N ")" ::: "memory");  \
        __builtin_amdgcn_s_barrier();                          \
    } while (0)

// ---------------------------------------------------------------------------
// prep_qk: feat1/feat2 fp32 -> fp16 staged tiles.
// Layout: [bz][tile128(6)][k0(18)][row(128)][chunk x(4)][8 halves], swizzle:
// chunk x holds k-elements (x ^ ((row>>1)&3))*8 .. +7.
// ---------------------------------------------------------------------------
__global__ __launch_bounds__(256) void prep_qk(const float* __restrict__ f1,
                                               const float* __restrict__ f2,
                                               char* __restrict__ q16,
                                               char* __restrict__ kv16,
                                               int b0) {
    int idx = blockIdx.x * 256 + threadIdx.x;
    int x   = idx & 3;
    int row = (idx >> 2) & 127;
    int t3  = idx >> 9;
    int k0  = t3 % 18;
    int t4  = t3 / 18;
    int ti  = t4 % 6;
    int bz  = t4 / 6;
    int kc  = x ^ ((row >> 1) & 3);
    size_t src = ((size_t)(b0 + bz) * C_ + ti * 128 + row) * HW_ + k0 * 32 + kc * 8;
    f32x4 a0 = *(const f32x4*)(f1 + src);
    f32x4 a1 = *(const f32x4*)(f1 + src + 4);
    f32x4 c0 = *(const f32x4*)(f2 + src);
    f32x4 c1 = *(const f32x4*)(f2 + src + 4);
    half8 ha, hb;
    #pragma unroll
    for (int e = 0; e < 4; ++e) {
        ha[e] = (_Float16)a0[e]; ha[4 + e] = (_Float16)a1[e];
        hb[e] = (_Float16)c0[e]; hb[4 + e] = (_Float16)c1[e];
    }
    *(half8*)(q16  + (size_t)idx * 16) = ha;
    *(half8*)(kv16 + (size_t)idx * 16) = hb;
}

// ---------------------------------------------------------------------------
// prep_vt: feat2 -> transposed fp16 tiles for PV's B operand.
// Layout: [bz][tj192(3)][k0(24)][n(192)][chunk x(4)][8], swizzle x^((n>>1)&3).
// ---------------------------------------------------------------------------
__global__ __launch_bounds__(256) void prep_vt(const float* __restrict__ f2,
                                               char* __restrict__ vt, int b0) {
    __shared__ float Vsh[32 * 201];
    int k0 = blockIdx.x, tj = blockIdx.y, bz = blockIdx.z;
    int b  = b0 + bz;
    int t  = threadIdx.x;
    #pragma unroll
    for (int p = 0; p < 6; ++p) {
        int fidx = p * 256 + t;
        int dd = fidx / 48, c4 = fidx % 48;
        f32x4 v = *(const f32x4*)(f2 + ((size_t)b * C_ + k0 * 32 + dd) * HW_ + tj * 192 + c4 * 4);
        #pragma unroll
        for (int e = 0; e < 4; ++e) Vsh[dd * 201 + c4 * 4 + e] = v[e];
    }
    __syncthreads();
    char* ob = vt + ((size_t)(bz * 3 + tj) * PV_STEPS + k0) * V_TILE_B;
    #pragma unroll
    for (int p = 0; p < 3; ++p) {
        int o = p * 256 + t;
        int x = o & 3, n = o >> 2;
        int kc = x ^ ((n >> 1) & 3);
        half8 h;
        #pragma unroll
        for (int j = 0; j < 8; ++j) h[j] = (_Float16)Vsh[(kc * 8 + j) * 201 + n];
        *(half8*)(ob + o * 16) = h;
    }
}

// ---------------------------------------------------------------------------
// qk3: attn = q @ kv^T. Tile 256x256, BK=32, 8 waves (2Mx4N, wave 128x64),
// depth-2 prefetch, triple-buffered LDS, counted vmcnt.
// ---------------------------------------------------------------------------
__global__ __launch_bounds__(512, 2) void qk3(const char* __restrict__ q16,
                                              const char* __restrict__ kv16,
                                              float* __restrict__ attn,
                                              int nwg) {
    __shared__ __align__(16) char As[3][16384];   // 256 rows x 64 B
    __shared__ __align__(16) char Bs[3][16384];
    const int wg = xcd_swz(blockIdx.x, nwg);
    const int tj2 = wg % 3, tmp = wg / 3, ti2 = tmp % 3, bz = tmp / 3;
    const int t = threadIdx.x, lane = t & 63, w = t >> 6;
    const int rsub = lane >> 2;          // row within a 1KB load chunk
    const int cb   = (lane & 3) * 16;    // byte within 64B row

    // per-lane global sources: wave w stages rows 32w..32w+31 (2x 16-row loads)
    const char* srcA[2];
    const char* srcB[2];
    #pragma unroll
    for (int l = 0; l < 2; ++l) {
        int row = 32 * w + 16 * l + rsub;
        srcA[l] = q16  + ((size_t)(bz * 6 + ti2 * 2 + (row >> 7)) * QK_STEPS) * A_TILE_B
                       + (row & 127) * 64 + cb;
        srcB[l] = kv16 + ((size_t)(bz * 6 + tj2 * 2 + (row >> 7)) * QK_STEPS) * A_TILE_B
                       + (row & 127) * 64 + cb;
    }

    const int wr = (w >> 2) * 128, wc = (w & 3) * 64;
    const int r = lane & 15, cg = lane >> 4;
    int offA[8], offB[4];
    #pragma unroll
    for (int m = 0; m < 8; ++m) {
        int ra = wr + m * 16 + r;
        offA[m] = ra * 64 + ((cg ^ ((ra >> 1) & 3)) << 4);
    }
    #pragma unroll
    for (int n = 0; n < 4; ++n) {
        int rb = wc + n * 16 + r;
        offB[n] = rb * 64 + ((cg ^ ((rb >> 1) & 3)) << 4);
    }

    f32x4 acc[8][4] = {};

#define QSTAGE(it, bb) do {                                         \
        g2l16(srcA[0] + (size_t)(it) * 8192, &As[bb][w * 2048]);          \
        g2l16(srcA[1] + (size_t)(it) * 8192, &As[bb][w * 2048 + 1024]);   \
        g2l16(srcB[0] + (size_t)(it) * 8192, &Bs[bb][w * 2048]);          \
        g2l16(srcB[1] + (size_t)(it) * 8192, &Bs[bb][w * 2048 + 1024]);   \
    } while (0)

    QSTAGE(0, 0);
    QSTAGE(1, 1);
    for (int it = 0; it < QK_STEPS; ++it) {
        const int cur = it % 3;
        LGKM0_BARRIER();                      // all waves done reading buf[(it-1)%3]
        if (it + 2 < QK_STEPS) {
            QSTAGE(it + 2, (it + 2) % 3);     // depth-2: it+1, it+2 in flight
            VMCNT_BARRIER(8);                 // stage(it) landed
        } else if (it + 2 == QK_STEPS) {
            VMCNT_BARRIER(4);
        } else {
            VMCNT_BARRIER(0);
        }
        half8 a[8], bb8[4];
        #pragma unroll
        for (int m = 0; m < 8; ++m) a[m]  = *(const half8*)(&As[cur][offA[m]]);
        #pragma unroll
        for (int n = 0; n < 4; ++n) bb8[n] = *(const half8*)(&Bs[cur][offB[n]]);
        __builtin_amdgcn_s_setprio(1);
        #pragma unroll
        for (int m = 0; m < 8; ++m)
            #pragma unroll
            for (int n = 0; n < 4; ++n)
                acc[m][n] = __builtin_amdgcn_mfma_f32_16x16x32_f16(a[m], bb8[n], acc[m][n], 0, 0, 0);
        __builtin_amdgcn_s_setprio(0);
    }
#undef QSTAGE

    float* ab = attn + ((size_t)bz * C_ + ti2 * 256) * C_ + tj2 * 256;
    const int col = lane & 15, rbase = (lane >> 4) * 4;
    #pragma unroll
    for (int m = 0; m < 8; ++m)
        #pragma unroll
        for (int n = 0; n < 4; ++n)
            #pragma unroll
            for (int rg = 0; rg < 4; ++rg)
                ab[(size_t)(wr + m * 16 + rbase + rg) * C_ + wc + n * 16 + col] = acc[m][n][rg];
}

// ---------------------------------------------------------------------------
// softmax_p16: row softmax of attn (fp32) -> P fp16 staged layout, gamma folded.
// ---------------------------------------------------------------------------
__global__ __launch_bounds__(256) void softmax_p16(const float* __restrict__ attn,
                                                   char* __restrict__ p16,
                                                   const float* __restrict__ gamma) {
    const int R    = blockIdx.x * 4 + (threadIdx.x >> 6);
    const int lane = threadIdx.x & 63;
    const int bz   = R / C_;
    const int c    = R - bz * C_;
    const float* p = attn + (size_t)R * C_;

    f32x4 v[3];
    float mx = -1e30f;
    #pragma unroll
    for (int u = 0; u < 3; ++u) {
        v[u] = *(const f32x4*)(p + (size_t)(lane + 64 * u) * 4);
        #pragma unroll
        for (int e = 0; e < 4; ++e) mx = fmaxf(mx, v[u][e]);
    }
    #pragma unroll
    for (int o = 32; o > 0; o >>= 1) mx = fmaxf(mx, __shfl_xor(mx, o));

    float s = 0.f;
    #pragma unroll
    for (int u = 0; u < 3; ++u)
        #pragma unroll
        for (int e = 0; e < 4; ++e) {
            v[u][e] = __expf(v[u][e] - mx);
            s += v[u][e];
        }
    #pragma unroll
    for (int o = 32; o > 0; o >>= 1) s += __shfl_xor(s, o);
    const float scale = gamma[0] / s;

    const int sw = (c >> 1) & 3;
    char* tb = p16 + ((size_t)(bz * 6 + (c >> 7)) * PV_STEPS) * A_TILE_B;
    #pragma unroll
    for (int u = 0; u < 3; ++u) {
        int d0 = 4 * lane + 256 * u;
        int k0 = d0 >> 5;
        int x  = ((d0 >> 3) & 3) ^ sw;
        char* addr = tb + (size_t)k0 * A_TILE_B + (c & 127) * 64 + x * 16 + (d0 & 7) * 2;
        half4 hv;
        #pragma unroll
        for (int e = 0; e < 4; ++e) hv[e] = (_Float16)(v[u][e] * scale);
        *(half4*)addr = hv;
    }
}

// ---------------------------------------------------------------------------
// pv3: out = (gamma*P)@V + feat1. Tile 256x192, BK=32, 8 waves (wave 128x48),
// depth-2 prefetch, triple-buffered LDS. Waves 0-3 stage P (4 loads each),
// waves 4-7 stage V (3 loads each); per-wave-group counted vmcnt.
// ---------------------------------------------------------------------------
__global__ __launch_bounds__(512, 2) void pv3(const char* __restrict__ p16,
                                              const char* __restrict__ vt,
                                              const float* __restrict__ f1,
                                              float* __restrict__ out,
                                              int b0, int nwg) {
    __shared__ __align__(16) char Ps[3][16384];   // 256 rows x 64 B
    __shared__ __align__(16) char Vs[3][12288];   // 192 rows x 64 B
    const int wg = xcd_swz(blockIdx.x, nwg);
    const int tj = wg % 3, tmp = wg / 3, ti2 = tmp % 3, bz = tmp / 3;
    const int t = threadIdx.x, lane = t & 63, w = t >> 6;
    const int rsub = lane >> 2;
    const int cb   = (lane & 3) * 16;

    // staging sources
    const char* srcP[4];
    const char* srcV[3];
    if (w < 4) {
        #pragma unroll
        for (int l = 0; l < 4; ++l) {
            int row = 64 * w + 16 * l + rsub;
            srcP[l] = p16 + ((size_t)(bz * 6 + ti2 * 2 + (row >> 7)) * PV_STEPS) * A_TILE_B
                          + (row & 127) * 64 + cb;
        }
    } else {
        int v = w - 4;
        #pragma unroll
        for (int l = 0; l < 3; ++l) {
            int n = 48 * v + 16 * l + rsub;
            srcV[l] = vt + ((size_t)(bz * 3 + tj) * PV_STEPS) * V_TILE_B + n * 64 + cb;
        }
    }

    const int wr = (w >> 2) * 128, wc = (w & 3) * 48;
    const int r = lane & 15, cg = lane >> 4;
    int offA[8], offB[3];
    #pragma unroll
    for (int m = 0; m < 8; ++m) {
        int ra = wr + m * 16 + r;
        offA[m] = ra * 64 + ((cg ^ ((ra >> 1) & 3)) << 4);
    }
    #pragma unroll
    for (int n = 0; n < 3; ++n) {
        int rb = wc + n * 16 + r;
        offB[n] = rb * 64 + ((cg ^ ((rb >> 1) & 3)) << 4);
    }

    f32x4 acc[8][3] = {};

#define PSTAGE(it, bb) do {                                                   \
        if (w < 4) {                                                          \
            g2l16(srcP[0] + (size_t)(it) * 8192,  &Ps[bb][w * 4096]);         \
            g2l16(srcP[1] + (size_t)(it) * 8192,  &Ps[bb][w * 4096 + 1024]);  \
            g2l16(srcP[2] + (size_t)(it) * 8192,  &Ps[bb][w * 4096 + 2048]);  \
            g2l16(srcP[3] + (size_t)(it) * 8192,  &Ps[bb][w * 4096 + 3072]);  \
        } else {                                                              \
            g2l16(srcV[0] + (size_t)(it) * 12288, &Vs[bb][(w - 4) * 3072]);         \
            g2l16(srcV[1] + (size_t)(it) * 12288, &Vs[bb][(w - 4) * 3072 + 1024]);  \
            g2l16(srcV[2] + (size_t)(it) * 12288, &Vs[bb][(w - 4) * 3072 + 2048]);  \
        }                                                                     \
    } while (0)
#define PVM_BAR(NA, NB) do {                                                  \
        if (w < 4) asm volatile("s_waitcnt vmcnt(" #NA ")" ::: "memory");     \
        else       asm volatile("s_waitcnt vmcnt(" #NB ")" ::: "memory");     \
        __builtin_amdgcn_s_barrier();                                         \
    } while (0)

    PSTAGE(0, 0);
    PSTAGE(1, 1);
    for (int it = 0; it < PV_STEPS; ++it) {
        const int cur = it % 3;
        LGKM0_BARRIER();
        if (it + 2 < PV_STEPS) {
            PSTAGE(it + 2, (it + 2) % 3);
            PVM_BAR(8, 6);
        } else if (it + 2 == PV_STEPS) {
            PVM_BAR(4, 3);
        } else {
            PVM_BAR(0, 0);
        }
        half8 a[8], bb8[3];
        #pragma unroll
        for (int m = 0; m < 8; ++m) a[m]  = *(const half8*)(&Ps[cur][offA[m]]);
        #pragma unroll
        for (int n = 0; n < 3; ++n) bb8[n] = *(const half8*)(&Vs[cur][offB[n]]);
        __builtin_amdgcn_s_setprio(1);
        #pragma unroll
        for (int m = 0; m < 8; ++m)
            #pragma unroll
            for (int n = 0; n < 3; ++n)
                acc[m][n] = __builtin_amdgcn_mfma_f32_16x16x32_f16(a[m], bb8[n], acc[m][n], 0, 0, 0);
        __builtin_amdgcn_s_setprio(0);
    }
#undef PSTAGE
#undef PVM_BAR

    const int b = b0 + bz;
    const float* f1b = f1 + ((size_t)b * C_ + ti2 * 256) * HW_ + tj * 192;
    float*       ob  = out + ((size_t)b * C_ + ti2 * 256) * HW_ + tj * 192;
    const int col = lane & 15, rbase = (lane >> 4) * 4;
    #pragma unroll
    for (int m = 0; m < 8; ++m)
        #pragma unroll
        for (int n = 0; n < 3; ++n)
            #pragma unroll
            for (int rg = 0; rg < 4; ++rg) {
                int rr = wr + m * 16 + rbase + rg;
                int cc = wc + n * 16 + col;
                ob[(size_t)rr * HW_ + cc] = acc[m][n][rg] + f1b[(size_t)rr * HW_ + cc];
            }
}

// ---------------------------------------------------------------------------
extern "C" void kernel_launch(void* const* d_in, const int* in_sizes, int n_in,
                              void* d_out, int out_size, void* d_ws, size_t ws_size,
                              hipStream_t stream) {
    const float* feat1 = (const float*)d_in[0];
    const float* feat2 = (const float*)d_in[1];
    const float* gamma = (const float*)d_in[2];
    float* out = (float*)d_out;

    const size_t SZ_Q    = (size_t)C_ * HW_ * 2;
    const size_t SZ_ATTN = (size_t)C_ * C_  * 4;
    const size_t SZ_P    = (size_t)C_ * C_  * 2;
    const size_t per_batch = SZ_ATTN + 3 * SZ_Q + SZ_P;

    int nb = (int)(ws_size / per_batch);
    if (nb < 1) nb = 1;
    if (nb > B_) nb = B_;

    char* ws    = (char*)d_ws;
    float* attn = (float*)ws;
    char* q16   = ws + (size_t)nb * SZ_ATTN;
    char* kv16  = q16 + (size_t)nb * SZ_Q;
    char* vtb   = kv16 + (size_t)nb * SZ_Q;
    char* p16   = vtb + (size_t)nb * SZ_Q;

    for (int b0 = 0; b0 < B_; b0 += nb) {
        int cur = (B_ - b0 < nb) ? (B_ - b0) : nb;
        prep_qk<<<cur * 216, 256, 0, stream>>>(feat1, feat2, q16, kv16, b0);
        prep_vt<<<dim3(PV_STEPS, 3, cur), 256, 0, stream>>>(feat2, vtb, b0);
        qk3<<<cur * 9, 512, 0, stream>>>(q16, kv16, attn, cur * 9);
        softmax_p16<<<cur * (C_ / 4), 256, 0, stream>>>(attn, p16, gamma);
        pv3<<<cur * 9, 512, 0, stream>>>(p16, vtb, feat1, out, b0, cur * 9);
    }
}

// Round 6
// 146.548 us; speedup vs baseline: 1.3293x; 1.3293x over previous
//
#include <hip/hip_runtime.h>

// Problem constants: B=32, C=768, H=W=24 -> HW=576
#define B_  32
#define C_  768
#define HW_ 576

#define NCQ 18               // HW_/32 k-chunks (qk)
#define NCP 24               // C_/32 k-chunks (pv)

typedef _Float16 half8 __attribute__((ext_vector_type(8)));
typedef _Float16 half4 __attribute__((ext_vector_type(4)));
typedef float    f32x4 __attribute__((ext_vector_type(4)));

__device__ __forceinline__ void g2l16(const void* g, void* l) {
    __builtin_amdgcn_global_load_lds(
        (const __attribute__((address_space(1))) unsigned int*)g,
        (__attribute__((address_space(3))) unsigned int*)l, 16, 0, 0);
}

// bijective XCD-aware block swizzle (m204): same-batch tiles share an XCD L2
__device__ __forceinline__ int xcd_swz(int orig, int nwg) {
    int q = nwg >> 3, rr = nwg & 7;
    int xcd = orig & 7, idx = orig >> 3;
    int base = (xcd < rr) ? xcd * (q + 1) : rr * (q + 1) + (xcd - rr) * q;
    return base + idx;
}

// ---------------------------------------------------------------------------
// prep_all: feat1/feat2 fp32 -> q16, kv16 (row-major fp16 staged tiles) AND
// vt (transposed fp16 tiles). One pass over f2 (prep_vt folded in).
// q16/kv16 layout: [bz][ti128(6)][k0(18)][row(128)][x(4)][8 halves],
//   chunk x holds k-elems (x ^ ((row>>1)&3))*8..+7.
// vt layout: [bz][tj192(3)][k0(24)][n(192)][x(4)][8], elem (n,kk)=f2[b][k][n],
//   chunk x holds k-chunk x ^ ((n>>1)&3).
// ---------------------------------------------------------------------------
__global__ __launch_bounds__(256) void prep_all(const float* __restrict__ f1,
                                                const float* __restrict__ f2,
                                                char* __restrict__ q16,
                                                char* __restrict__ kv16,
                                                char* __restrict__ vt,
                                                int b0, int nqk) {
    const int bid = blockIdx.x;
    if (bid < nqk) {
        int idx = bid * 256 + threadIdx.x;
        int x   = idx & 3;
        int row = (idx >> 2) & 127;
        int t3  = idx >> 9;
        int k0  = t3 % 18;
        int t4  = t3 / 18;
        int ti  = t4 % 6;
        int bz  = t4 / 6;
        int kc  = x ^ ((row >> 1) & 3);
        size_t src = ((size_t)(b0 + bz) * C_ + ti * 128 + row) * HW_ + k0 * 32 + kc * 8;
        f32x4 a0 = *(const f32x4*)(f1 + src);
        f32x4 a1 = *(const f32x4*)(f1 + src + 4);
        f32x4 c0 = *(const f32x4*)(f2 + src);
        f32x4 c1 = *(const f32x4*)(f2 + src + 4);
        half8 ha, hb;
        #pragma unroll
        for (int e = 0; e < 4; ++e) {
            ha[e] = (_Float16)a0[e]; ha[4 + e] = (_Float16)a1[e];
            hb[e] = (_Float16)c0[e]; hb[4 + e] = (_Float16)c1[e];
        }
        *(half8*)(q16  + (size_t)idx * 16) = ha;
        *(half8*)(kv16 + (size_t)idx * 16) = hb;
    } else {
        int idx = (bid - nqk) * 256 + threadIdx.x;
        int bz  = idx / 55296;
        int wl  = idx % 55296;
        int tj  = wl / 18432;
        int r   = wl % 18432;
        int k0  = r / 768;
        int r2  = r % 768;
        int n   = r2 >> 2;
        int x   = r2 & 3;
        int kc  = x ^ ((n >> 1) & 3);
        int c0  = k0 * 32 + kc * 8;
        const float* s = f2 + ((size_t)(b0 + bz) * C_ + c0) * HW_ + tj * 192 + n;
        half8 h;
        #pragma unroll
        for (int j = 0; j < 8; ++j) h[j] = (_Float16)s[(size_t)j * HW_];
        *(half8*)(vt + ((size_t)(bz * 3 + tj) * NCP + k0) * 12288 + n * 64 + x * 16) = h;
    }
}

// ---------------------------------------------------------------------------
// qk6: attn = q @ kv^T. Tile 192x192, 8 waves (4Mx2N, wave 48x96), BK=32,
// ring-3 LDS (72 KB -> 2 blocks/CU), depth-2 counted-vmcnt fine pipeline.
// Per chunk-phase: issue 3 g2l (c+2) | vmcnt(6) | bar | 9 ds_read | 18 MFMA | bar
// ---------------------------------------------------------------------------
__global__ __launch_bounds__(512, 4) void qk6(const char* __restrict__ q16,
                                              const char* __restrict__ kv16,
                                              float* __restrict__ attn,
                                              int nwg) {
    __shared__ __align__(16) char S[3][24576];   // per slot: A 12KB | B 12KB
    const int wg = xcd_swz(blockIdx.x, nwg);
    const int bz = wg >> 4, rr0 = wg & 15, ti = rr0 >> 2, tj = rr0 & 3;
    const int t = threadIdx.x, lane = t & 63, w = t >> 6;
    const int rsub = lane >> 2, cb = (lane & 3) * 16;

    // staging sources: 3 loads/wave/chunk (A 12 loads + B 12 loads per block)
    const char *p0, *p1, *p2;
    int o0, o1, o2;
    {
        auto arow = [&](int l) {
            int gr = ti * 192 + 16 * l + rsub;
            return q16 + ((size_t)(bz * 6 + (gr >> 7)) * NCQ) * 8192 + (gr & 127) * 64 + cb;
        };
        auto brow = [&](int l) {
            int gd = tj * 192 + 16 * l + rsub;
            return kv16 + ((size_t)(bz * 6 + (gd >> 7)) * NCQ) * 8192 + (gd & 127) * 64 + cb;
        };
        if (w < 4) {
            p0 = arow(2 * w);     o0 = (2 * w) * 1024;
            p1 = arow(2 * w + 1); o1 = (2 * w + 1) * 1024;
            p2 = brow(8 + w);     o2 = 12288 + (8 + w) * 1024;
        } else {
            int v = w - 4;
            p0 = brow(2 * v);     o0 = 12288 + (2 * v) * 1024;
            p1 = brow(2 * v + 1); o1 = 12288 + (2 * v + 1) * 1024;
            p2 = arow(8 + v);     o2 = (8 + v) * 1024;
        }
    }

    const int wr = (w >> 1) * 48, wc = (w & 1) * 96;
    const int r16 = lane & 15, cg = lane >> 4;
    int offA[3], offB[6];
    #pragma unroll
    for (int m = 0; m < 3; ++m) {
        int ra = wr + m * 16 + r16;
        offA[m] = ra * 64 + ((cg ^ ((ra >> 1) & 3)) << 4);
    }
    #pragma unroll
    for (int n = 0; n < 6; ++n) {
        int rb = wc + n * 16 + r16;
        offB[n] = 12288 + rb * 64 + ((cg ^ ((rb >> 1) & 3)) << 4);
    }

    f32x4 acc[3][6] = {};

#define STG(SLOT) do {                          \
        char* sb_ = &S[SLOT][0];                \
        g2l16(p0, sb_ + o0);                    \
        g2l16(p1, sb_ + o1);                    \
        g2l16(p2, sb_ + o2);                    \
        p0 += 8192; p1 += 8192; p2 += 8192;     \
    } while (0)

    STG(0); STG(1);
    int rd = 0, st = 2;
    for (int c = 0; c < NCQ; ++c) {
        if (c + 2 < NCQ) {
            STG(st); st = (st == 2) ? 0 : st + 1;
            asm volatile("s_waitcnt vmcnt(6)" ::: "memory");
        } else if (c + 2 == NCQ) {
            asm volatile("s_waitcnt vmcnt(3)" ::: "memory");
        } else {
            asm volatile("s_waitcnt vmcnt(0)" ::: "memory");
        }
        __builtin_amdgcn_s_barrier();
        const char* sb = &S[rd][0];
        rd = (rd == 2) ? 0 : rd + 1;
        half8 a0 = *(const half8*)(sb + offA[0]);
        half8 a1 = *(const half8*)(sb + offA[1]);
        half8 a2 = *(const half8*)(sb + offA[2]);
        __builtin_amdgcn_s_setprio(1);
        #pragma unroll
        for (int n = 0; n < 6; ++n) {
            half8 bn = *(const half8*)(sb + offB[n]);
            acc[0][n] = __builtin_amdgcn_mfma_f32_16x16x32_f16(a0, bn, acc[0][n], 0, 0, 0);
            acc[1][n] = __builtin_amdgcn_mfma_f32_16x16x32_f16(a1, bn, acc[1][n], 0, 0, 0);
            acc[2][n] = __builtin_amdgcn_mfma_f32_16x16x32_f16(a2, bn, acc[2][n], 0, 0, 0);
        }
        __builtin_amdgcn_s_setprio(0);
        __builtin_amdgcn_s_barrier();
    }
#undef STG

    float* ab = attn + ((size_t)bz * C_ + ti * 192) * C_ + tj * 192;
    const int col = lane & 15, rbase = (lane >> 4) * 4;
    #pragma unroll
    for (int m = 0; m < 3; ++m)
        #pragma unroll
        for (int n = 0; n < 6; ++n)
            #pragma unroll
            for (int rg = 0; rg < 4; ++rg)
                ab[(size_t)(wr + m * 16 + rbase + rg) * C_ + wc + n * 16 + col] = acc[m][n][rg];
}

// ---------------------------------------------------------------------------
// softmax_p16: row softmax of attn (fp32) -> P fp16 staged layout, gamma folded.
// ---------------------------------------------------------------------------
__global__ __launch_bounds__(256) void softmax_p16(const float* __restrict__ attn,
                                                   char* __restrict__ p16,
                                                   const float* __restrict__ gamma) {
    const int R    = blockIdx.x * 4 + (threadIdx.x >> 6);
    const int lane = threadIdx.x & 63;
    const int bz   = R / C_;
    const int c    = R - bz * C_;
    const float* p = attn + (size_t)R * C_;

    f32x4 v[3];
    float mx = -1e30f;
    #pragma unroll
    for (int u = 0; u < 3; ++u) {
        v[u] = *(const f32x4*)(p + (size_t)(lane + 64 * u) * 4);
        #pragma unroll
        for (int e = 0; e < 4; ++e) mx = fmaxf(mx, v[u][e]);
    }
    #pragma unroll
    for (int o = 32; o > 0; o >>= 1) mx = fmaxf(mx, __shfl_xor(mx, o));

    float s = 0.f;
    #pragma unroll
    for (int u = 0; u < 3; ++u)
        #pragma unroll
        for (int e = 0; e < 4; ++e) {
            v[u][e] = __expf(v[u][e] - mx);
            s += v[u][e];
        }
    #pragma unroll
    for (int o = 32; o > 0; o >>= 1) s += __shfl_xor(s, o);
    const float scale = gamma[0] / s;

    const int sw = (c >> 1) & 3;
    char* tb = p16 + ((size_t)(bz * 6 + (c >> 7)) * NCP) * 8192;
    #pragma unroll
    for (int u = 0; u < 3; ++u) {
        int d0 = 4 * lane + 256 * u;
        int k0 = d0 >> 5;
        int x  = ((d0 >> 3) & 3) ^ sw;
        char* addr = tb + (size_t)k0 * 8192 + (c & 127) * 64 + x * 16 + (d0 & 7) * 2;
        half4 hv;
        #pragma unroll
        for (int e = 0; e < 4; ++e) hv[e] = (_Float16)(v[u][e] * scale);
        *(half4*)addr = hv;
    }
}

// ---------------------------------------------------------------------------
// pv6: out = (gamma*P)@V + feat1. Tile 192x192, 8 waves, BK=32, ring-3,
// depth-2 counted-vmcnt fine pipeline. Same schedule as qk6.
// ---------------------------------------------------------------------------
__global__ __launch_bounds__(512, 4) void pv6(const char* __restrict__ p16,
                                              const char* __restrict__ vt,
                                              const float* __restrict__ f1,
                                              float* __restrict__ out,
                                              int b0, int nwg) {
    __shared__ __align__(16) char S[3][24576];
    const int wg = xcd_swz(blockIdx.x, nwg);
    const int bz = wg / 12, rr0 = wg % 12, ti = rr0 / 3, tj = rr0 % 3;
    const int t = threadIdx.x, lane = t & 63, w = t >> 6;
    const int rsub = lane >> 2, cb = (lane & 3) * 16;

    const char *p0, *p1, *p2;
    int o0, o1, o2;
    long s0, s1, s2;
    {
        auto prow = [&](int l) {
            int gr = ti * 192 + 16 * l + rsub;
            return p16 + ((size_t)(bz * 6 + (gr >> 7)) * NCP) * 8192 + (gr & 127) * 64 + cb;
        };
        auto vrow = [&](int l) {
            int gn = 16 * l + rsub;
            return vt + ((size_t)(bz * 3 + tj) * NCP) * 12288 + gn * 64 + cb;
        };
        if (w < 4) {
            p0 = prow(2 * w);     o0 = (2 * w) * 1024;     s0 = 8192;
            p1 = prow(2 * w + 1); o1 = (2 * w + 1) * 1024; s1 = 8192;
            p2 = vrow(8 + w);     o2 = 12288 + (8 + w) * 1024; s2 = 12288;
        } else {
            int v = w - 4;
            p0 = vrow(2 * v);     o0 = 12288 + (2 * v) * 1024;     s0 = 12288;
            p1 = vrow(2 * v + 1); o1 = 12288 + (2 * v + 1) * 1024; s1 = 12288;
            p2 = prow(8 + v);     o2 = (8 + v) * 1024;             s2 = 8192;
        }
    }

    const int wr = (w >> 1) * 48, wc = (w & 1) * 96;
    const int r16 = lane & 15, cg = lane >> 4;
    int offA[3], offB[6];
    #pragma unroll
    for (int m = 0; m < 3; ++m) {
        int ra = wr + m * 16 + r16;
        offA[m] = ra * 64 + ((cg ^ ((ra >> 1) & 3)) << 4);
    }
    #pragma unroll
    for (int n = 0; n < 6; ++n) {
        int rb = wc + n * 16 + r16;
        offB[n] = 12288 + rb * 64 + ((cg ^ ((rb >> 1) & 3)) << 4);
    }

    f32x4 acc[3][6] = {};

#define STG(SLOT) do {                          \
        char* sb_ = &S[SLOT][0];                \
        g2l16(p0, sb_ + o0);                    \
        g2l16(p1, sb_ + o1);                    \
        g2l16(p2, sb_ + o2);                    \
        p0 += s0; p1 += s1; p2 += s2;           \
    } while (0)

    STG(0); STG(1);
    int rd = 0, st = 2;
    for (int c = 0; c < NCP; ++c) {
        if (c + 2 < NCP) {
            STG(st); st = (st == 2) ? 0 : st + 1;
            asm volatile("s_waitcnt vmcnt(6)" ::: "memory");
        } else if (c + 2 == NCP) {
            asm volatile("s_waitcnt vmcnt(3)" ::: "memory");
        } else {
            asm volatile("s_waitcnt vmcnt(0)" ::: "memory");
        }
        __builtin_amdgcn_s_barrier();
        const char* sb = &S[rd][0];
        rd = (rd == 2) ? 0 : rd + 1;
        half8 a0 = *(const half8*)(sb + offA[0]);
        half8 a1 = *(const half8*)(sb + offA[1]);
        half8 a2 = *(const half8*)(sb + offA[2]);
        __builtin_amdgcn_s_setprio(1);
        #pragma unroll
        for (int n = 0; n < 6; ++n) {
            half8 bn = *(const half8*)(sb + offB[n]);
            acc[0][n] = __builtin_amdgcn_mfma_f32_16x16x32_f16(a0, bn, acc[0][n], 0, 0, 0);
            acc[1][n] = __builtin_amdgcn_mfma_f32_16x16x32_f16(a1, bn, acc[1][n], 0, 0, 0);
            acc[2][n] = __builtin_amdgcn_mfma_f32_16x16x32_f16(a2, bn, acc[2][n], 0, 0, 0);
        }
        __builtin_amdgcn_s_setprio(0);
        __builtin_amdgcn_s_barrier();
    }
#undef STG

    const int b = b0 + bz;
    const float* f1b = f1 + ((size_t)b * C_ + ti * 192) * HW_ + tj * 192;
    float*       ob  = out + ((size_t)b * C_ + ti * 192) * HW_ + tj * 192;
    const int col = lane & 15, rbase = (lane >> 4) * 4;
    #pragma unroll
    for (int m = 0; m < 3; ++m)
        #pragma unroll
        for (int n = 0; n < 6; ++n)
            #pragma unroll
            for (int rg = 0; rg < 4; ++rg) {
                int r2 = wr + m * 16 + rbase + rg;
                int c2 = wc + n * 16 + col;
                ob[(size_t)r2 * HW_ + c2] = acc[m][n][rg] + f1b[(size_t)r2 * HW_ + c2];
            }
}

// ---------------------------------------------------------------------------
extern "C" void kernel_launch(void* const* d_in, const int* in_sizes, int n_in,
                              void* d_out, int out_size, void* d_ws, size_t ws_size,
                              hipStream_t stream) {
    const float* feat1 = (const float*)d_in[0];
    const float* feat2 = (const float*)d_in[1];
    const float* gamma = (const float*)d_in[2];
    float* out = (float*)d_out;

    const size_t SZ_Q    = (size_t)C_ * HW_ * 2;
    const size_t SZ_ATTN = (size_t)C_ * C_  * 4;
    const size_t SZ_P    = (size_t)C_ * C_  * 2;
    const size_t per_batch = SZ_ATTN + 3 * SZ_Q + SZ_P;

    int nb = (int)(ws_size / per_batch);
    if (nb < 1) nb = 1;
    if (nb > B_) nb = B_;

    char* ws    = (char*)d_ws;
    float* attn = (float*)ws;
    char* q16   = ws + (size_t)nb * SZ_ATTN;
    char* kv16  = q16 + (size_t)nb * SZ_Q;
    char* vtb   = kv16 + (size_t)nb * SZ_Q;
    char* p16   = vtb + (size_t)nb * SZ_Q;

    for (int b0 = 0; b0 < B_; b0 += nb) {
        int cur = (B_ - b0 < nb) ? (B_ - b0) : nb;
        prep_all<<<cur * 432, 256, 0, stream>>>(feat1, feat2, q16, kv16, vtb, b0, cur * 216);
        qk6<<<cur * 16, 512, 0, stream>>>(q16, kv16, attn, cur * 16);
        softmax_p16<<<cur * 192, 256, 0, stream>>>(attn, p16, gamma);
        pv6<<<cur * 12, 512, 0, stream>>>(p16, vtb, feat1, out, b0, cur * 12);
    }
}